// Round 13
// baseline (282.720 us; speedup 1.0000x reference)
//
#include <hip/hip_runtime.h>

#define S_LEN 4096
#define HID   2048
#define NHEAD 16
#define HDIM  128
// 1/sqrt(128) * log2(e): Q pre-scale so softmax can use exp2 directly
#define QSCALE_L2E 0.12751664352f

typedef float  f32x4  __attribute__((ext_vector_type(4)));
typedef float  f32x16 __attribute__((ext_vector_type(16)));
typedef __bf16 bf16x8 __attribute__((ext_vector_type(8)));
typedef unsigned u32x4 __attribute__((ext_vector_type(4)));
typedef unsigned u32x2 __attribute__((ext_vector_type(2)));

#define MFMA16(a, b, c) __builtin_amdgcn_mfma_f32_16x16x32_bf16((a), (b), (c), 0, 0, 0)
#define MFMA32(a, b, c) __builtin_amdgcn_mfma_f32_32x32x16_bf16((a), (b), (c), 0, 0, 0)

__device__ __forceinline__ void gld16(const void* g, void* l) {
  __builtin_amdgcn_global_load_lds(
      (const __attribute__((address_space(1))) void*)(unsigned long long)(g),
      (__attribute__((address_space(3))) void*)(unsigned long long)(l),
      16, 0, 0);
}

__device__ __forceinline__ unsigned short f2bf(float f) {
  union { float f; unsigned u; } v; v.f = f;
  unsigned r = v.u + 0x7FFFu + ((v.u >> 16) & 1u);
  return (unsigned short)(r >> 16);
}
__device__ __forceinline__ float bf2f(unsigned short h) {
  union { unsigned u; float f; } v; v.u = ((unsigned)h) << 16;
  return v.f;
}
__device__ __forceinline__ unsigned cvtpk_bf16(float a, float b) {
  unsigned r;
  asm("v_cvt_pk_bf16_f32 %0, %1, %2" : "=v"(r) : "v"(a), "v"(b));
  return r;
}
// lane l<32 / l>=32 exchange: ret[0] = {a.lo || b.lo}, ret[1] = {a.hi || b.hi}
__device__ __forceinline__ u32x2 pls(unsigned a, unsigned b) {
  return __builtin_amdgcn_permlane32_swap(a, b, false, false);
}
__device__ __forceinline__ float asf(unsigned u) { return __builtin_bit_cast(float, u); }
__device__ __forceinline__ unsigned asu(float f) { return __builtin_bit_cast(unsigned, f); }

// ---------------- merged f32 -> bf16 conversion (hidden | wqkv | wdense) -------
__global__ __launch_bounds__(256) void cvt3_kernel(
    const float* __restrict__ s0, const float* __restrict__ s1,
    const float* __restrict__ s2, unsigned short* __restrict__ d0,
    unsigned short* __restrict__ d1, unsigned short* __restrict__ d2) {
  int i = (blockIdx.x * 256 + threadIdx.x) * 4;
  const float* src; unsigned short* dst;
  if (i < 8388608) { src = s0; dst = d0; }
  else if (i < 20971520) { src = s1 - 8388608; dst = d1 - 8388608; }
  else { src = s2 - 20971520; dst = d2 - 20971520; }
  const float4 v = *(const float4*)(src + i);
  ushort4 o;
  o.x = f2bf(v.x); o.y = f2bf(v.y); o.z = f2bf(v.z); o.w = f2bf(v.w);
  *(ushort4*)(dst + i) = o;
}

// ---------------- QKV GEMM: BM=256 x BN=128 x BK=32, 512 thr, 72KB LDS ---------
// 3 bufs x 24KB -> 2 blocks/CU = 4 waves/SIMD (the 147KB BK=64 version was
// 1 block/CU = 2 waves/SIMD -- same occupancy disease attn had).
// Stage 2 ahead, counted vmcnt(3) (3 loads/tile), one barrier per K-tile.
// bm-major XCD swizzle; fused partial-RoPE scatter epilogue.
__global__ __launch_bounds__(512, 4) void gemm_qkv_kernel(
    const unsigned short* __restrict__ A, const unsigned short* __restrict__ B,
    unsigned short* __restrict__ Qb, unsigned short* __restrict__ Kb,
    unsigned short* __restrict__ Vt) {
  __shared__ __align__(16) unsigned char sm[73728];  // 3 x (A 16K | B 8K)
  constexpr int K = HID;
  constexpr int NT = K / 32;  // 64
  const int b = (int)blockIdx.x;
  const int bm = (b & 7) * 2 + ((b >> 3) & 1);   // bm-major per XCD (bijective, 16 bm)
  const int bn = b >> 4;                         // 48 bn
  const int row0 = bm * 256, col0 = bn * 128;
  const int tid = threadIdx.x;
  const int wid = tid >> 6, lane = tid & 63;
  const int g = lane >> 4, r16 = lane & 15;
  const int wm = wid >> 1, wn = wid & 1;

  auto stageA = [&](int t, int bufo) {
    const int k0 = t * 32;
#pragma unroll
    for (int cc = 0; cc < 2; ++cc) {
      const int chunk = cc * 512 + tid;           // 1024 x 16B = 16KB
      const int r = chunk >> 2, c3 = chunk & 3;   // 64B rows
      gld16(A + (row0 + r) * K + k0 + ((c3 ^ (r & 3)) << 3), sm + bufo + chunk * 16);
    }
  };
  auto stageB = [&](int t, int bufo) {
    const int k0 = t * 32;
    const int r = tid >> 2, c3 = tid & 3;         // 512 x 16B = 8KB
    gld16(B + (col0 + r) * K + k0 + ((c3 ^ (r & 3)) << 3), sm + bufo + 16384 + tid * 16);
  };

  f32x4 acc[4][4] = {};
  int aoff[4], boff[4];
#pragma unroll
  for (int m = 0; m < 4; ++m) {
    const int r = wm * 64 + m * 16 + r16;
    aoff[m] = r * 64 + ((g * 16) ^ ((r & 3) << 4));
  }
#pragma unroll
  for (int n = 0; n < 4; ++n) {
    const int r = wn * 64 + n * 16 + r16;
    boff[n] = 16384 + r * 64 + ((g * 16) ^ ((r & 3) << 4));
  }

  stageA(0, 0); stageB(0, 0);
  stageA(1, 24576); stageB(1, 24576);
  asm volatile("s_waitcnt vmcnt(3)" ::: "memory");  // buf0 landed; stage(1) flying
  __builtin_amdgcn_s_barrier();
  __builtin_amdgcn_sched_barrier(0);

  int curo = 0, stgo = 49152;
  for (int t = 0; t < NT; ++t) {
    const bool st = (t + 2 < NT);
    bf16x8 af[4], bfv[4];
#pragma unroll
    for (int m = 0; m < 4; ++m) af[m] = *(const bf16x8*)(sm + curo + aoff[m]);
#pragma unroll
    for (int n = 0; n < 4; ++n) bfv[n] = *(const bf16x8*)(sm + curo + boff[n]);
    if (st) { stageA(t + 2, stgo); stageB(t + 2, stgo); }
    __builtin_amdgcn_s_setprio(1);
#pragma unroll
    for (int m = 0; m < 4; ++m)
#pragma unroll
      for (int n = 0; n < 4; ++n) acc[m][n] = MFMA16(af[m], bfv[n], acc[m][n]);
    __builtin_amdgcn_s_setprio(0);
    if (st) asm volatile("s_waitcnt vmcnt(3)" ::: "memory");  // publish buf(t+1)
    else    asm volatile("s_waitcnt vmcnt(0)" ::: "memory");
    __builtin_amdgcn_s_barrier();
    __builtin_amdgcn_sched_barrier(0);
    curo = (curo == 49152) ? 0 : curo + 24576;
    stgo = (stgo == 49152) ? 0 : stgo + 24576;
  }

  const int type = bn % 3, p = bn / 3;
  if (type <= 1) {
    unsigned short* Ob = (type == 0) ? Qb : Kb;
    const float qs = (type == 0) ? QSCALE_L2E : 1.0f;
    const float invf = exp2f(-(float)r16 * 0.8304820237218406f);  // 10000^(-r16/16)
#pragma unroll
    for (int m = 0; m < 4; ++m) {
      const int s0 = row0 + wm * 64 + m * 16 + g * 4;
      if (wn == 0) {
        // n=0,1 hold the rotary dims: pair (d=r16, d=16+r16), NeoX rotate_half
#pragma unroll
        for (int r = 0; r < 4; ++r) {
          const float ang = (float)(s0 + r) * invf;
          const float c = cosf(ang), sn = sinf(ang);
          const float x = acc[m][0][r] * qs, y = acc[m][1][r] * qs;
          unsigned short* dst = Ob + (p * S_LEN + s0 + r) * HDIM;
          dst[r16]      = f2bf(x * c - y * sn);
          dst[16 + r16] = f2bf(y * c + x * sn);
        }
#pragma unroll
        for (int n = 2; n < 4; ++n)
#pragma unroll
          for (int r = 0; r < 4; ++r)
            Ob[(p * S_LEN + s0 + r) * HDIM + n * 16 + r16] = f2bf(acc[m][n][r] * qs);
      } else {
#pragma unroll
        for (int n = 0; n < 4; ++n)
#pragma unroll
          for (int r = 0; r < 4; ++r)
            Ob[(p * S_LEN + s0 + r) * HDIM + 64 + n * 16 + r16] = f2bf(acc[m][n][r] * qs);
      }
    }
  } else {
#pragma unroll
    for (int m = 0; m < 4; ++m) {
      const int s0 = row0 + wm * 64 + m * 16 + g * 4;
#pragma unroll
      for (int n = 0; n < 4; ++n) {
        const int d = wn * 64 + n * 16 + r16;
        ushort4 o;
        o.x = f2bf(acc[m][n][0]); o.y = f2bf(acc[m][n][1]);
        o.z = f2bf(acc[m][n][2]); o.w = f2bf(acc[m][n][3]);
        *(ushort4*)(Vt + (p * HDIM + d) * S_LEN + s0) = o;
      }
    }
  }
}

// ---------------- dense GEMM: BM=128 x BN=128 x BK=32, 256 thr, 48KB LDS -------
// grid 512 = 2 blocks/CU (vs 256 = 1/CU before). Stage 2 ahead, vmcnt(4).
__global__ __launch_bounds__(256, 4) void gemm_dense_kernel(
    const unsigned short* __restrict__ A, const unsigned short* __restrict__ B,
    const float* __restrict__ bias, float* __restrict__ out) {
  __shared__ __align__(16) unsigned char sm[49152];  // 3 x (A 8K | B 8K)
  constexpr int K = HID;
  constexpr int NT = K / 32;  // 64
  const int b = (int)blockIdx.x;
  const int bm = (b & 7) * 4 + ((b >> 3) & 3);   // bm-major per XCD (bijective, 32 bm)
  const int bn = b >> 5;                         // 16 bn
  const int row0 = bm * 128, col0 = bn * 128;
  const int tid = threadIdx.x;
  const int wid = tid >> 6, lane = tid & 63;
  const int g = lane >> 4, r16 = lane & 15;
  const int wm = wid >> 1, wn = wid & 1;

  auto stageA = [&](int t, int bufo) {
    const int k0 = t * 32;
#pragma unroll
    for (int cc = 0; cc < 2; ++cc) {
      const int chunk = cc * 256 + tid;           // 512 x 16B = 8KB
      const int r = chunk >> 2, c3 = chunk & 3;
      gld16(A + (row0 + r) * K + k0 + ((c3 ^ (r & 3)) << 3), sm + bufo + chunk * 16);
    }
  };
  auto stageB = [&](int t, int bufo) {
    const int k0 = t * 32;
#pragma unroll
    for (int cc = 0; cc < 2; ++cc) {
      const int chunk = cc * 256 + tid;
      const int r = chunk >> 2, c3 = chunk & 3;
      gld16(B + (col0 + r) * K + k0 + ((c3 ^ (r & 3)) << 3), sm + bufo + 8192 + chunk * 16);
    }
  };

  f32x4 acc[4][4] = {};
  int aoff[4], boff[4];
#pragma unroll
  for (int m = 0; m < 4; ++m) {
    const int r = wm * 64 + m * 16 + r16;
    aoff[m] = r * 64 + ((g * 16) ^ ((r & 3) << 4));
  }
#pragma unroll
  for (int n = 0; n < 4; ++n) {
    const int r = wn * 64 + n * 16 + r16;
    boff[n] = 8192 + r * 64 + ((g * 16) ^ ((r & 3) << 4));
  }

  stageA(0, 0); stageB(0, 0);
  stageA(1, 16384); stageB(1, 16384);
  asm volatile("s_waitcnt vmcnt(4)" ::: "memory");
  __builtin_amdgcn_s_barrier();
  __builtin_amdgcn_sched_barrier(0);

  int curo = 0, stgo = 32768;
  for (int t = 0; t < NT; ++t) {
    const bool st = (t + 2 < NT);
    bf16x8 af[4], bfv[4];
#pragma unroll
    for (int m = 0; m < 4; ++m) af[m] = *(const bf16x8*)(sm + curo + aoff[m]);
#pragma unroll
    for (int n = 0; n < 4; ++n) bfv[n] = *(const bf16x8*)(sm + curo + boff[n]);
    if (st) { stageA(t + 2, stgo); stageB(t + 2, stgo); }
    __builtin_amdgcn_s_setprio(1);
#pragma unroll
    for (int m = 0; m < 4; ++m)
#pragma unroll
      for (int n = 0; n < 4; ++n) acc[m][n] = MFMA16(af[m], bfv[n], acc[m][n]);
    __builtin_amdgcn_s_setprio(0);
    if (st) asm volatile("s_waitcnt vmcnt(4)" ::: "memory");
    else    asm volatile("s_waitcnt vmcnt(0)" ::: "memory");
    __builtin_amdgcn_s_barrier();
    __builtin_amdgcn_sched_barrier(0);
    curo = (curo == 32768) ? 0 : curo + 16384;
    stgo = (stgo == 32768) ? 0 : stgo + 16384;
  }

#pragma unroll
  for (int m = 0; m < 4; ++m) {
    const int s0 = row0 + wm * 64 + m * 16 + g * 4;
#pragma unroll
    for (int n = 0; n < 4; ++n) {
      const int col = col0 + wn * 64 + n * 16 + r16;
      const float bv = bias[col];
#pragma unroll
      for (int r = 0; r < 4; ++r)
        out[(s0 + r) * HID + col] = acc[m][n][r] + bv;
    }
  }
}

// ---------------- causal flash attention: in-block KV-split, 8 waves ----------
// (R12-exact, measured 119.8us / Occ 20.6% / MfmaUtil 24.4%.)
__global__ __launch_bounds__(512, 2) void attn_kernel(
    const unsigned short* __restrict__ Qb, const unsigned short* __restrict__ Kb,
    const unsigned short* __restrict__ Vt, unsigned short* __restrict__ Ctx) {
  __shared__ __align__(16) unsigned char sm[81920];
  const int b = (int)blockIdx.x;
  const int p = b & 15;
  const int qt = (b < 256) ? (b >> 4) : 47 - (b >> 4);
  const int tid = threadIdx.x, wid = tid >> 6, lane = tid & 63;
  const int g = wid >> 2, wv = wid & 3, gtid = tid & 255;
  const int l31 = lane & 31, hi = lane >> 5;
  const int xr = (l31 & 7) << 4;
  const int GB = g * 40960;

  const int q0w = qt * 128 + wv * 32;
  const int qg = q0w + l31;
  const int Th = 2 * (qt + 1);
  const int np = qt + 1;
  const int tg0 = g * Th;

  auto stageK = [&](int tg, int ko) {
    const unsigned short* kb = Kb + (p * S_LEN + tg * 32) * HDIM;
#pragma unroll
    for (int c = 0; c < 2; ++c) {
      const int chunk = c * 256 + gtid;
      const int j = chunk >> 4, cb = chunk & 15;
      gld16(kb + j * HDIM + ((cb ^ (j & 7)) << 3), sm + ko + chunk * 16);
    }
  };
  auto stageV = [&](int tg, int vo) {
    const unsigned short* vbase = Vt + p * HDIM * S_LEN + tg * 32;
#pragma unroll
    for (int c = 0; c < 2; ++c) {
      const int chunk = c * 256 + gtid;
      const int d = chunk >> 2, cb = chunk & 3;
      gld16(vbase + d * S_LEN + ((cb ^ (d & 3)) << 3), sm + vo + chunk * 16);
    }
  };

  bf16x8 qf[8];
  f32x16 acc[4] = {};
  float m_s = -1e30f, l_s = 0.f;

  auto qk = [&](f32x16& s, const unsigned char* kl) {
    __builtin_amdgcn_s_setprio(1);
#pragma unroll
    for (int dd = 0; dd < 8; ++dd) {
      bf16x8 k0 = *(const bf16x8*)(kl + l31 * 256 + (((dd * 2 + hi) << 4) ^ xr));
      s = MFMA32(k0, qf[dd], s);
    }
    __builtin_amdgcn_s_setprio(0);
  };

  auto smpv = [&](f32x16& s, int tg, int vo) {
    const unsigned char* vl = sm + vo;
    if (tg * 32 + 31 > q0w) {
#pragma unroll
      for (int r = 0; r < 16; ++r) {
        const int kv0 = tg * 32 + ((r & 3) + 8 * (r >> 2)) + 4 * hi;
        if (kv0 > qg) s[r] = -1e30f;
      }
    }
    float mx[8];
#pragma unroll
    for (int r = 0; r < 8; ++r) mx[r] = fmaxf(s[r], s[r + 8]);
#pragma unroll
    for (int r = 0; r < 4; ++r) mx[r] = fmaxf(mx[r], mx[r + 4]);
    mx[0] = fmaxf(fmaxf(mx[0], mx[2]), fmaxf(mx[1], mx[3]));
    float pm;
    {
      u32x2 e = pls(asu(mx[0]), asu(mx[0]));
      pm = fmaxf(asf(e.x), asf(e.y));
    }
    if (__any(pm > m_s + 11.5f)) {
      const float mn = fmaxf(m_s, pm);
      const float scl = exp2f(m_s - mn);
#pragma unroll
      for (int d32 = 0; d32 < 4; ++d32)
#pragma unroll
        for (int r = 0; r < 16; ++r) acc[d32][r] *= scl;
      l_s *= scl;
      m_s = mn;
    }
#pragma unroll
    for (int r = 0; r < 16; ++r) s[r] = exp2f(s[r] - m_s);
    bf16x8 pf[2];
#define PACKB(B, SV, base)                                                        \
    {                                                                             \
      unsigned X0 = cvtpk_bf16(SV[base + 0], SV[base + 1]);                       \
      unsigned X1 = cvtpk_bf16(SV[base + 2], SV[base + 3]);                       \
      unsigned Y0 = cvtpk_bf16(SV[base + 4], SV[base + 5]);                       \
      unsigned Y1 = cvtpk_bf16(SV[base + 6], SV[base + 7]);                       \
      u32x2 e0 = pls(X0, Y0);                                                     \
      u32x2 e1 = pls(X1, Y1);                                                     \
      u32x4 pw;                                                                   \
      pw.x = e0.x; pw.y = e1.x; pw.z = e0.y; pw.w = e1.y;                         \
      pf[B] = __builtin_bit_cast(bf16x8, pw);                                     \
    }
    PACKB(0, s, 0)
    PACKB(1, s, 8)
#undef PACKB
    __builtin_amdgcn_s_setprio(1);
#pragma unroll
    for (int d32 = 0; d32 < 4; ++d32) {
      const int d = d32 * 32 + l31;
#pragma unroll
      for (int bb = 0; bb < 2; ++bb) {
        bf16x8 vf = *(const bf16x8*)(vl + d * 64 + ((((bb * 2 + hi) << 4)) ^ ((l31 & 3) << 4)));
        acc[d32] = MFMA32(vf, pf[bb], acc[d32]);
      }
    }
    __builtin_amdgcn_s_setprio(0);
    float s_[8];
#pragma unroll
    for (int r = 0; r < 8; ++r) s_[r] = s[r] + s[r + 8];
#pragma unroll
    for (int r = 0; r < 4; ++r) s_[r] += s_[r + 4];
    const float rs = (s_[0] + s_[1]) + (s_[2] + s_[3]);
    u32x2 e = pls(asu(rs), asu(rs));
    l_s += asf(e.x) + asf(e.y);
  };

  {
    const unsigned short* qp_ = Qb + (p * S_LEN + qg) * HDIM + hi * 8;
#pragma unroll
    for (int dd = 0; dd < 8; ++dd) qf[dd] = *(const bf16x8*)(qp_ + dd * 16);
  }
  stageK(tg0, GB);
  stageV(tg0, GB + 16384);
  stageK(tg0 + 1, GB + 8192);
  stageV(tg0 + 1, GB + 24576);
  int vcur = GB + 16384, vnext = GB + 24576, vstage = GB + 32768;
  __syncthreads();
  f32x16 sA = {};
  qk(sA, sm + GB);
  __syncthreads();

  for (int tt = 0; tt < np; ++tt) {
    const bool more = (tt + 1 < np);
    const int t = tg0 + 2 * tt;
    f32x16 sB = {};
    qk(sB, sm + GB + 8192);
    if (more) { stageK(t + 2, GB); stageV(t + 2, vstage); }
    smpv(sA, t, vcur);
    { int tmp = vcur; vcur = vnext; vnext = vstage; vstage = tmp; }
    __syncthreads();
    if (more) {
      sA = {};
      qk(sA, sm + GB);
      stageK(t + 3, GB + 8192);
      stageV(t + 3, vstage);
    }
    smpv(sB, t + 1, vcur);
    { int tmp = vcur; vcur = vnext; vnext = vstage; vstage = tmp; }
    __syncthreads();
  }

  if (g == 1) {
    const int base = wv * 16384;
#pragma unroll
    for (int d32 = 0; d32 < 4; ++d32)
#pragma unroll
      for (int k = 0; k < 4; ++k) {
        float4 v4;
        v4.x = acc[d32][k * 4 + 0]; v4.y = acc[d32][k * 4 + 1];
        v4.z = acc[d32][k * 4 + 2]; v4.w = acc[d32][k * 4 + 3];
        *(float4*)(sm + base + d32 * 4096 + k * 1024 + lane * 16) = v4;
      }
    if (hi == 0)
      *(float2*)(sm + 65536 + (wv * 32 + l31) * 8) = make_float2(m_s, l_s);
  }
  __syncthreads();
  if (g == 0) {
    const float2 ml1 = *(const float2*)(sm + 65536 + (wv * 32 + l31) * 8);
    const float mm = fmaxf(m_s, ml1.x);
    const float w0 = exp2f(m_s - mm), w1 = exp2f(ml1.x - mm);
    const float linv = 1.0f / (l_s * w0 + ml1.y * w1);
    unsigned short* cbase = Ctx + qg * HID + p * HDIM;
#pragma unroll
    for (int d32 = 0; d32 < 4; ++d32)
#pragma unroll
      for (int k = 0; k < 4; ++k) {
        const float4 o1 = *(const float4*)(sm + wv * 16384 + d32 * 4096 + k * 1024 + lane * 16);
        const float ov[4] = {o1.x, o1.y, o1.z, o1.w};
#pragma unroll
        for (int j = 0; j < 4; ++j) {
          const int d = d32 * 32 + j + 8 * k + 4 * hi;
          cbase[d] = f2bf((acc[d32][k * 4 + j] * w0 + ov[j] * w1) * linv);
        }
      }
  }
}

extern "C" void kernel_launch(void* const* d_in, const int* in_sizes, int n_in,
                              void* d_out, int out_size, void* d_ws, size_t ws_size,
                              hipStream_t stream) {
  (void)in_sizes; (void)n_in; (void)out_size; (void)ws_size;
  const float* hidden = (const float*)d_in[0];
  const float* wqkv   = (const float*)d_in[2];
  const float* wdense = (const float*)d_in[3];
  const float* bdense = (const float*)d_in[4];
  float* out = (float*)d_out;

  char* ws = (char*)d_ws;
  unsigned short* hiddenB = (unsigned short*)(ws);
  unsigned short* wqkvB   = (unsigned short*)(ws + 16777216);
  unsigned short* wdenseB = (unsigned short*)(ws + 41943040);
  unsigned short* Qb      = (unsigned short*)(ws + 50331648);
  unsigned short* Kb      = (unsigned short*)(ws + 67108864);
  unsigned short* Vt      = (unsigned short*)(ws + 83886080);
  unsigned short* ctxB    = (unsigned short*)(ws + 100663296);

  cvt3_kernel<<<24576, 256, 0, stream>>>(hidden, wqkv, wdense, hiddenB, wqkvB, wdenseB);
  gemm_qkv_kernel<<<768, 512, 0, stream>>>(hiddenB, wqkvB, Qb, Kb, Vt);
  attn_kernel<<<512, 512, 0, stream>>>(Qb, Kb, Vt, ctxB);
  gemm_dense_kernel<<<512, 256, 0, stream>>>(ctxB, wdenseB, bdense, out);
}

// Round 14
// 277.611 us; speedup vs baseline: 1.0184x; 1.0184x over previous
//
#include <hip/hip_runtime.h>

#define S_LEN 4096
#define HID   2048
#define NHEAD 16
#define HDIM  128
// 1/sqrt(128) * log2(e): Q pre-scale so softmax can use exp2 directly
#define QSCALE_L2E 0.12751664352f

typedef float  f32x4  __attribute__((ext_vector_type(4)));
typedef float  f32x16 __attribute__((ext_vector_type(16)));
typedef __bf16 bf16x8 __attribute__((ext_vector_type(8)));
typedef unsigned u32x4 __attribute__((ext_vector_type(4)));
typedef unsigned u32x2 __attribute__((ext_vector_type(2)));

#define MFMA16(a, b, c) __builtin_amdgcn_mfma_f32_16x16x32_bf16((a), (b), (c), 0, 0, 0)
#define MFMA32(a, b, c) __builtin_amdgcn_mfma_f32_32x32x16_bf16((a), (b), (c), 0, 0, 0)

__device__ __forceinline__ void gld16(const void* g, void* l) {
  __builtin_amdgcn_global_load_lds(
      (const __attribute__((address_space(1))) void*)(unsigned long long)(g),
      (__attribute__((address_space(3))) void*)(unsigned long long)(l),
      16, 0, 0);
}

__device__ __forceinline__ unsigned short f2bf(float f) {
  union { float f; unsigned u; } v; v.f = f;
  unsigned r = v.u + 0x7FFFu + ((v.u >> 16) & 1u);
  return (unsigned short)(r >> 16);
}
__device__ __forceinline__ float bf2f(unsigned short h) {
  union { unsigned u; float f; } v; v.u = ((unsigned)h) << 16;
  return v.f;
}
__device__ __forceinline__ unsigned cvtpk_bf16(float a, float b) {
  unsigned r;
  asm("v_cvt_pk_bf16_f32 %0, %1, %2" : "=v"(r) : "v"(a), "v"(b));
  return r;
}
// lane l<32 / l>=32 exchange: ret[0] = {a.lo || b.lo}, ret[1] = {a.hi || b.hi}
__device__ __forceinline__ u32x2 pls(unsigned a, unsigned b) {
  return __builtin_amdgcn_permlane32_swap(a, b, false, false);
}
__device__ __forceinline__ float asf(unsigned u) { return __builtin_bit_cast(float, u); }
__device__ __forceinline__ unsigned asu(float f) { return __builtin_bit_cast(unsigned, f); }

// ---------------- merged f32 -> bf16 conversion (hidden | wqkv | wdense) -------
__global__ __launch_bounds__(256) void cvt3_kernel(
    const float* __restrict__ s0, const float* __restrict__ s1,
    const float* __restrict__ s2, unsigned short* __restrict__ d0,
    unsigned short* __restrict__ d1, unsigned short* __restrict__ d2) {
  int i = (blockIdx.x * 256 + threadIdx.x) * 4;
  const float* src; unsigned short* dst;
  if (i < 8388608) { src = s0; dst = d0; }
  else if (i < 20971520) { src = s1 - 8388608; dst = d1 - 8388608; }
  else { src = s2 - 20971520; dst = d2 - 20971520; }
  const float4 v = *(const float4*)(src + i);
  ushort4 o;
  o.x = f2bf(v.x); o.y = f2bf(v.y); o.z = f2bf(v.z); o.w = f2bf(v.w);
  *(ushort4*)(dst + i) = o;
}

// ---------------- QKV GEMM: BM=256 x BN=128 x BK=32, 512 thr, 72KB LDS ---------
// (R13-exact, neutral vs BK=64.)
__global__ __launch_bounds__(512, 4) void gemm_qkv_kernel(
    const unsigned short* __restrict__ A, const unsigned short* __restrict__ B,
    unsigned short* __restrict__ Qb, unsigned short* __restrict__ Kb,
    unsigned short* __restrict__ Vt) {
  __shared__ __align__(16) unsigned char sm[73728];  // 3 x (A 16K | B 8K)
  constexpr int K = HID;
  constexpr int NT = K / 32;  // 64
  const int b = (int)blockIdx.x;
  const int bm = (b & 7) * 2 + ((b >> 3) & 1);   // bm-major per XCD (bijective, 16 bm)
  const int bn = b >> 4;                         // 48 bn
  const int row0 = bm * 256, col0 = bn * 128;
  const int tid = threadIdx.x;
  const int wid = tid >> 6, lane = tid & 63;
  const int g = lane >> 4, r16 = lane & 15;
  const int wm = wid >> 1, wn = wid & 1;

  auto stageA = [&](int t, int bufo) {
    const int k0 = t * 32;
#pragma unroll
    for (int cc = 0; cc < 2; ++cc) {
      const int chunk = cc * 512 + tid;           // 1024 x 16B = 16KB
      const int r = chunk >> 2, c3 = chunk & 3;   // 64B rows
      gld16(A + (row0 + r) * K + k0 + ((c3 ^ (r & 3)) << 3), sm + bufo + chunk * 16);
    }
  };
  auto stageB = [&](int t, int bufo) {
    const int k0 = t * 32;
    const int r = tid >> 2, c3 = tid & 3;         // 512 x 16B = 8KB
    gld16(B + (col0 + r) * K + k0 + ((c3 ^ (r & 3)) << 3), sm + bufo + 16384 + tid * 16);
  };

  f32x4 acc[4][4] = {};
  int aoff[4], boff[4];
#pragma unroll
  for (int m = 0; m < 4; ++m) {
    const int r = wm * 64 + m * 16 + r16;
    aoff[m] = r * 64 + ((g * 16) ^ ((r & 3) << 4));
  }
#pragma unroll
  for (int n = 0; n < 4; ++n) {
    const int r = wn * 64 + n * 16 + r16;
    boff[n] = 16384 + r * 64 + ((g * 16) ^ ((r & 3) << 4));
  }

  stageA(0, 0); stageB(0, 0);
  stageA(1, 24576); stageB(1, 24576);
  asm volatile("s_waitcnt vmcnt(3)" ::: "memory");  // buf0 landed; stage(1) flying
  __builtin_amdgcn_s_barrier();
  __builtin_amdgcn_sched_barrier(0);

  int curo = 0, stgo = 49152;
  for (int t = 0; t < NT; ++t) {
    const bool st = (t + 2 < NT);
    bf16x8 af[4], bfv[4];
#pragma unroll
    for (int m = 0; m < 4; ++m) af[m] = *(const bf16x8*)(sm + curo + aoff[m]);
#pragma unroll
    for (int n = 0; n < 4; ++n) bfv[n] = *(const bf16x8*)(sm + curo + boff[n]);
    if (st) { stageA(t + 2, stgo); stageB(t + 2, stgo); }
    __builtin_amdgcn_s_setprio(1);
#pragma unroll
    for (int m = 0; m < 4; ++m)
#pragma unroll
      for (int n = 0; n < 4; ++n) acc[m][n] = MFMA16(af[m], bfv[n], acc[m][n]);
    __builtin_amdgcn_s_setprio(0);
    if (st) asm volatile("s_waitcnt vmcnt(3)" ::: "memory");  // publish buf(t+1)
    else    asm volatile("s_waitcnt vmcnt(0)" ::: "memory");
    __builtin_amdgcn_s_barrier();
    __builtin_amdgcn_sched_barrier(0);
    curo = (curo == 49152) ? 0 : curo + 24576;
    stgo = (stgo == 49152) ? 0 : stgo + 24576;
  }

  const int type = bn % 3, p = bn / 3;
  if (type <= 1) {
    unsigned short* Ob = (type == 0) ? Qb : Kb;
    const float qs = (type == 0) ? QSCALE_L2E : 1.0f;
    const float invf = exp2f(-(float)r16 * 0.8304820237218406f);  // 10000^(-r16/16)
#pragma unroll
    for (int m = 0; m < 4; ++m) {
      const int s0 = row0 + wm * 64 + m * 16 + g * 4;
      if (wn == 0) {
        // n=0,1 hold the rotary dims: pair (d=r16, d=16+r16), NeoX rotate_half
#pragma unroll
        for (int r = 0; r < 4; ++r) {
          const float ang = (float)(s0 + r) * invf;
          const float c = cosf(ang), sn = sinf(ang);
          const float x = acc[m][0][r] * qs, y = acc[m][1][r] * qs;
          unsigned short* dst = Ob + (p * S_LEN + s0 + r) * HDIM;
          dst[r16]      = f2bf(x * c - y * sn);
          dst[16 + r16] = f2bf(y * c + x * sn);
        }
#pragma unroll
        for (int n = 2; n < 4; ++n)
#pragma unroll
          for (int r = 0; r < 4; ++r)
            Ob[(p * S_LEN + s0 + r) * HDIM + n * 16 + r16] = f2bf(acc[m][n][r] * qs);
      } else {
#pragma unroll
        for (int n = 0; n < 4; ++n)
#pragma unroll
          for (int r = 0; r < 4; ++r)
            Ob[(p * S_LEN + s0 + r) * HDIM + 64 + n * 16 + r16] = f2bf(acc[m][n][r] * qs);
      }
    }
  } else {
#pragma unroll
    for (int m = 0; m < 4; ++m) {
      const int s0 = row0 + wm * 64 + m * 16 + g * 4;
#pragma unroll
      for (int n = 0; n < 4; ++n) {
        const int d = wn * 64 + n * 16 + r16;
        ushort4 o;
        o.x = f2bf(acc[m][n][0]); o.y = f2bf(acc[m][n][1]);
        o.z = f2bf(acc[m][n][2]); o.w = f2bf(acc[m][n][3]);
        *(ushort4*)(Vt + (p * HDIM + d) * S_LEN + s0) = o;
      }
    }
  }
}

// ---------------- dense GEMM: BM=128 x BN=128 x BK=32, 256 thr, 48KB LDS -------
// (R13-exact.)
__global__ __launch_bounds__(256, 4) void gemm_dense_kernel(
    const unsigned short* __restrict__ A, const unsigned short* __restrict__ B,
    const float* __restrict__ bias, float* __restrict__ out) {
  __shared__ __align__(16) unsigned char sm[49152];  // 3 x (A 8K | B 8K)
  constexpr int K = HID;
  constexpr int NT = K / 32;  // 64
  const int b = (int)blockIdx.x;
  const int bm = (b & 7) * 4 + ((b >> 3) & 3);   // bm-major per XCD (bijective, 32 bm)
  const int bn = b >> 5;                         // 16 bn
  const int row0 = bm * 128, col0 = bn * 128;
  const int tid = threadIdx.x;
  const int wid = tid >> 6, lane = tid & 63;
  const int g = lane >> 4, r16 = lane & 15;
  const int wm = wid >> 1, wn = wid & 1;

  auto stageA = [&](int t, int bufo) {
    const int k0 = t * 32;
#pragma unroll
    for (int cc = 0; cc < 2; ++cc) {
      const int chunk = cc * 256 + tid;           // 512 x 16B = 8KB
      const int r = chunk >> 2, c3 = chunk & 3;
      gld16(A + (row0 + r) * K + k0 + ((c3 ^ (r & 3)) << 3), sm + bufo + chunk * 16);
    }
  };
  auto stageB = [&](int t, int bufo) {
    const int k0 = t * 32;
#pragma unroll
    for (int cc = 0; cc < 2; ++cc) {
      const int chunk = cc * 256 + tid;
      const int r = chunk >> 2, c3 = chunk & 3;
      gld16(B + (col0 + r) * K + k0 + ((c3 ^ (r & 3)) << 3), sm + bufo + 8192 + chunk * 16);
    }
  };

  f32x4 acc[4][4] = {};
  int aoff[4], boff[4];
#pragma unroll
  for (int m = 0; m < 4; ++m) {
    const int r = wm * 64 + m * 16 + r16;
    aoff[m] = r * 64 + ((g * 16) ^ ((r & 3) << 4));
  }
#pragma unroll
  for (int n = 0; n < 4; ++n) {
    const int r = wn * 64 + n * 16 + r16;
    boff[n] = 8192 + r * 64 + ((g * 16) ^ ((r & 3) << 4));
  }

  stageA(0, 0); stageB(0, 0);
  stageA(1, 16384); stageB(1, 16384);
  asm volatile("s_waitcnt vmcnt(4)" ::: "memory");
  __builtin_amdgcn_s_barrier();
  __builtin_amdgcn_sched_barrier(0);

  int curo = 0, stgo = 32768;
  for (int t = 0; t < NT; ++t) {
    const bool st = (t + 2 < NT);
    bf16x8 af[4], bfv[4];
#pragma unroll
    for (int m = 0; m < 4; ++m) af[m] = *(const bf16x8*)(sm + curo + aoff[m]);
#pragma unroll
    for (int n = 0; n < 4; ++n) bfv[n] = *(const bf16x8*)(sm + curo + boff[n]);
    if (st) { stageA(t + 2, stgo); stageB(t + 2, stgo); }
    __builtin_amdgcn_s_setprio(1);
#pragma unroll
    for (int m = 0; m < 4; ++m)
#pragma unroll
      for (int n = 0; n < 4; ++n) acc[m][n] = MFMA16(af[m], bfv[n], acc[m][n]);
    __builtin_amdgcn_s_setprio(0);
    if (st) asm volatile("s_waitcnt vmcnt(4)" ::: "memory");
    else    asm volatile("s_waitcnt vmcnt(0)" ::: "memory");
    __builtin_amdgcn_s_barrier();
    __builtin_amdgcn_sched_barrier(0);
    curo = (curo == 32768) ? 0 : curo + 16384;
    stgo = (stgo == 32768) ? 0 : stgo + 16384;
  }

#pragma unroll
  for (int m = 0; m < 4; ++m) {
    const int s0 = row0 + wm * 64 + m * 16 + g * 4;
#pragma unroll
    for (int n = 0; n < 4; ++n) {
      const int col = col0 + wn * 64 + n * 16 + r16;
      const float bv = bias[col];
#pragma unroll
      for (int r = 0; r < 4; ++r)
        out[(s0 + r) * HID + col] = acc[m][n][r] + bv;
    }
  }
}

// ---------------- causal flash attention: in-block KV-split, 8 waves ----------
// R12 structure; LDS XOR keys fixed for lane-parity decoupling:
//   K rows 256B: key = (row>>1)&7  (rows l31 and l31+32 share the key value;
//     even/odd lane cohorts now cover all 8 slots -> ~2-4-way, was 8-way)
//   V rows  64B: key = (d>>1)&3    (all 4 slots covered per cohort -> 4-way floor)
// Stage source and read use the same involution (both-sides rule).
__global__ __launch_bounds__(512, 2) void attn_kernel(
    const unsigned short* __restrict__ Qb, const unsigned short* __restrict__ Kb,
    const unsigned short* __restrict__ Vt, unsigned short* __restrict__ Ctx) {
  __shared__ __align__(16) unsigned char sm[81920];
  const int b = (int)blockIdx.x;
  const int p = b & 15;
  const int qt = (b < 256) ? (b >> 4) : 47 - (b >> 4);
  const int tid = threadIdx.x, wid = tid >> 6, lane = tid & 63;
  const int g = wid >> 2, wv = wid & 3, gtid = tid & 255;
  const int l31 = lane & 31, hi = lane >> 5;
  const int xrK = ((l31 >> 1) & 7) << 4;   // K read key (same for rows l31, l31+32)
  const int xrV = ((l31 >> 1) & 3) << 4;   // V read key (d = d32*32 + l31)
  const int GB = g * 40960;

  const int q0w = qt * 128 + wv * 32;
  const int qg = q0w + l31;
  const int Th = 2 * (qt + 1);
  const int np = qt + 1;
  const int tg0 = g * Th;

  auto stageK = [&](int tg, int ko) {
    const unsigned short* kb = Kb + (p * S_LEN + tg * 32) * HDIM;
#pragma unroll
    for (int c = 0; c < 2; ++c) {
      const int chunk = c * 256 + gtid;
      const int j = chunk >> 4, cb = chunk & 15;
      gld16(kb + j * HDIM + ((cb ^ ((j >> 1) & 7)) << 3), sm + ko + chunk * 16);
    }
  };
  auto stageV = [&](int tg, int vo) {
    const unsigned short* vbase = Vt + p * HDIM * S_LEN + tg * 32;
#pragma unroll
    for (int c = 0; c < 2; ++c) {
      const int chunk = c * 256 + gtid;
      const int d = chunk >> 2, cb = chunk & 3;
      gld16(vbase + d * S_LEN + ((cb ^ ((d >> 1) & 3)) << 3), sm + vo + chunk * 16);
    }
  };

  bf16x8 qf[8];
  f32x16 acc[4] = {};
  float m_s = -1e30f, l_s = 0.f;

  auto qk = [&](f32x16& s, const unsigned char* kl) {
    __builtin_amdgcn_s_setprio(1);
#pragma unroll
    for (int dd = 0; dd < 8; ++dd) {
      bf16x8 k0 = *(const bf16x8*)(kl + l31 * 256 + (((dd * 2 + hi) << 4) ^ xrK));
      s = MFMA32(k0, qf[dd], s);
    }
    __builtin_amdgcn_s_setprio(0);
  };

  auto smpv = [&](f32x16& s, int tg, int vo) {
    const unsigned char* vl = sm + vo;
    if (tg * 32 + 31 > q0w) {
#pragma unroll
      for (int r = 0; r < 16; ++r) {
        const int kv0 = tg * 32 + ((r & 3) + 8 * (r >> 2)) + 4 * hi;
        if (kv0 > qg) s[r] = -1e30f;
      }
    }
    float mx[8];
#pragma unroll
    for (int r = 0; r < 8; ++r) mx[r] = fmaxf(s[r], s[r + 8]);
#pragma unroll
    for (int r = 0; r < 4; ++r) mx[r] = fmaxf(mx[r], mx[r + 4]);
    mx[0] = fmaxf(fmaxf(mx[0], mx[2]), fmaxf(mx[1], mx[3]));
    float pm;
    {
      u32x2 e = pls(asu(mx[0]), asu(mx[0]));
      pm = fmaxf(asf(e.x), asf(e.y));
    }
    if (__any(pm > m_s + 11.5f)) {
      const float mn = fmaxf(m_s, pm);
      const float scl = exp2f(m_s - mn);
#pragma unroll
      for (int d32 = 0; d32 < 4; ++d32)
#pragma unroll
        for (int r = 0; r < 16; ++r) acc[d32][r] *= scl;
      l_s *= scl;
      m_s = mn;
    }
#pragma unroll
    for (int r = 0; r < 16; ++r) s[r] = exp2f(s[r] - m_s);
    bf16x8 pf[2];
#define PACKB(B, SV, base)                                                        \
    {                                                                             \
      unsigned X0 = cvtpk_bf16(SV[base + 0], SV[base + 1]);                       \
      unsigned X1 = cvtpk_bf16(SV[base + 2], SV[base + 3]);                       \
      unsigned Y0 = cvtpk_bf16(SV[base + 4], SV[base + 5]);                       \
      unsigned Y1 = cvtpk_bf16(SV[base + 6], SV[base + 7]);                       \
      u32x2 e0 = pls(X0, Y0);                                                     \
      u32x2 e1 = pls(X1, Y1);                                                     \
      u32x4 pw;                                                                   \
      pw.x = e0.x; pw.y = e1.x; pw.z = e0.y; pw.w = e1.y;                         \
      pf[B] = __builtin_bit_cast(bf16x8, pw);                                     \
    }
    PACKB(0, s, 0)
    PACKB(1, s, 8)
#undef PACKB
    __builtin_amdgcn_s_setprio(1);
#pragma unroll
    for (int d32 = 0; d32 < 4; ++d32) {
      const int d = d32 * 32 + l31;
#pragma unroll
      for (int bb = 0; bb < 2; ++bb) {
        bf16x8 vf = *(const bf16x8*)(vl + d * 64 + (((bb * 2 + hi) << 4) ^ xrV));
        acc[d32] = MFMA32(vf, pf[bb], acc[d32]);
      }
    }
    __builtin_amdgcn_s_setprio(0);
    float s_[8];
#pragma unroll
    for (int r = 0; r < 8; ++r) s_[r] = s[r] + s[r + 8];
#pragma unroll
    for (int r = 0; r < 4; ++r) s_[r] += s_[r + 4];
    const float rs = (s_[0] + s_[1]) + (s_[2] + s_[3]);
    u32x2 e = pls(asu(rs), asu(rs));
    l_s += asf(e.x) + asf(e.y);
  };

  {
    const unsigned short* qp_ = Qb + (p * S_LEN + qg) * HDIM + hi * 8;
#pragma unroll
    for (int dd = 0; dd < 8; ++dd) qf[dd] = *(const bf16x8*)(qp_ + dd * 16);
  }
  stageK(tg0, GB);
  stageV(tg0, GB + 16384);
  stageK(tg0 + 1, GB + 8192);
  stageV(tg0 + 1, GB + 24576);
  int vcur = GB + 16384, vnext = GB + 24576, vstage = GB + 32768;
  __syncthreads();
  f32x16 sA = {};
  qk(sA, sm + GB);
  __syncthreads();

  for (int tt = 0; tt < np; ++tt) {
    const bool more = (tt + 1 < np);
    const int t = tg0 + 2 * tt;
    f32x16 sB = {};
    qk(sB, sm + GB + 8192);
    if (more) { stageK(t + 2, GB); stageV(t + 2, vstage); }
    smpv(sA, t, vcur);
    { int tmp = vcur; vcur = vnext; vnext = vstage; vstage = tmp; }
    __syncthreads();
    if (more) {
      sA = {};
      qk(sA, sm + GB);
      stageK(t + 3, GB + 8192);
      stageV(t + 3, vstage);
    }
    smpv(sB, t + 1, vcur);
    { int tmp = vcur; vcur = vnext; vnext = vstage; vstage = tmp; }
    __syncthreads();
  }

  if (g == 1) {
    const int base = wv * 16384;
#pragma unroll
    for (int d32 = 0; d32 < 4; ++d32)
#pragma unroll
      for (int k = 0; k < 4; ++k) {
        float4 v4;
        v4.x = acc[d32][k * 4 + 0]; v4.y = acc[d32][k * 4 + 1];
        v4.z = acc[d32][k * 4 + 2]; v4.w = acc[d32][k * 4 + 3];
        *(float4*)(sm + base + d32 * 4096 + k * 1024 + lane * 16) = v4;
      }
    if (hi == 0)
      *(float2*)(sm + 65536 + (wv * 32 + l31) * 8) = make_float2(m_s, l_s);
  }
  __syncthreads();
  if (g == 0) {
    const float2 ml1 = *(const float2*)(sm + 65536 + (wv * 32 + l31) * 8);
    const float mm = fmaxf(m_s, ml1.x);
    const float w0 = exp2f(m_s - mm), w1 = exp2f(ml1.x - mm);
    const float linv = 1.0f / (l_s * w0 + ml1.y * w1);
    unsigned short* cbase = Ctx + qg * HID + p * HDIM;
#pragma unroll
    for (int d32 = 0; d32 < 4; ++d32)
#pragma unroll
      for (int k = 0; k < 4; ++k) {
        const float4 o1 = *(const float4*)(sm + wv * 16384 + d32 * 4096 + k * 1024 + lane * 16);
        const float ov[4] = {o1.x, o1.y, o1.z, o1.w};
#pragma unroll
        for (int j = 0; j < 4; ++j) {
          const int d = d32 * 32 + j + 8 * k + 4 * hi;
          cbase[d] = f2bf((acc[d32][k * 4 + j] * w0 + ov[j] * w1) * linv);
        }
      }
  }
}

extern "C" void kernel_launch(void* const* d_in, const int* in_sizes, int n_in,
                              void* d_out, int out_size, void* d_ws, size_t ws_size,
                              hipStream_t stream) {
  (void)in_sizes; (void)n_in; (void)out_size; (void)ws_size;
  const float* hidden = (const float*)d_in[0];
  const float* wqkv   = (const float*)d_in[2];
  const float* wdense = (const float*)d_in[3];
  const float* bdense = (const float*)d_in[4];
  float* out = (float*)d_out;

  char* ws = (char*)d_ws;
  unsigned short* hiddenB = (unsigned short*)(ws);
  unsigned short* wqkvB   = (unsigned short*)(ws + 16777216);
  unsigned short* wdenseB = (unsigned short*)(ws + 41943040);
  unsigned short* Qb      = (unsigned short*)(ws + 50331648);
  unsigned short* Kb      = (unsigned short*)(ws + 67108864);
  unsigned short* Vt      = (unsigned short*)(ws + 83886080);
  unsigned short* ctxB    = (unsigned short*)(ws + 100663296);

  cvt3_kernel<<<24576, 256, 0, stream>>>(hidden, wqkv, wdense, hiddenB, wqkvB, wdenseB);
  gemm_qkv_kernel<<<768, 512, 0, stream>>>(hiddenB, wqkvB, Qb, Kb, Vt);
  attn_kernel<<<512, 512, 0, stream>>>(Qb, Kb, Vt, ctxB);
  gemm_dense_kernel<<<512, 256, 0, stream>>>(ctxB, wdenseB, bdense, out);
}